// Round 14
// baseline (66.373 us; speedup 1.0000x reference)
//
#include <hip/hip_runtime.h>
#include <math.h>

#define NPTS 4096
#define NB 4
#define EPSF 1e-6f

// ============================================================================
// gravity_align + t_center (exact reference arithmetic; bit-exact R1-R13).
// ============================================================================
__device__ __forceinline__ void gravity_align_rt(
    const float* __restrict__ g_p, const float* __restrict__ g_q,
    const float* sums, int b, float* R_out, float* t_out) {
    float gpx = g_p[3 * b + 0], gpy = g_p[3 * b + 1], gpz = g_p[3 * b + 2];
    float gqx = g_q[3 * b + 0], gqy = g_q[3 * b + 1], gqz = g_q[3 * b + 2];
    float nu = sqrtf(gpx * gpx + gpy * gpy + gpz * gpz);
    float du = fmaxf(nu, EPSF);
    float ux = gpx / du, uy = gpy / du, uz = gpz / du;
    float nv = sqrtf(gqx * gqx + gqy * gqy + gqz * gqz);
    float dv = fmaxf(nv, EPSF);
    float vx = gqx / dv, vy = gqy / dv, vz = gqz / dv;

    float ax = uy * vz - uz * vy;
    float ay = uz * vx - ux * vz;
    float az = ux * vy - uy * vx;
    float an = sqrtf(ax * ax + ay * ay + az * az);
    float dot = ux * vx + uy * vy + uz * vz;
    dot = fminf(1.0f, fmaxf(-1.0f, dot));
    bool parallel = (an < 1e-6f);

    float kx = ax / (an + EPSF), ky = ay / (an + EPSF), kz = az / (an + EPSF);
    float theta = acosf(dot);
    float st = sinf(theta), ct = cosf(theta);

    float K[9] = {0.f, -kz, ky,  kz, 0.f, -kx,  -ky, kx, 0.f};
    float KK[9];
    for (int i = 0; i < 3; ++i)
        for (int j = 0; j < 3; ++j) {
            float s2 = 0.f;
            for (int l = 0; l < 3; ++l) s2 += K[i * 3 + l] * K[l * 3 + j];
            KK[i * 3 + j] = s2;
        }
    float R[9];
    for (int i = 0; i < 9; ++i) {
        float I = (i == 0 || i == 4 || i == 8) ? 1.f : 0.f;
        R[i] = I + st * K[i] + (1.f - ct) * KK[i];
    }
    if (parallel) {
        if (dot < 0.f) {
            float bx, by, bz;
            if (fabsf(ux) < 0.9f) { bx = 1.f; by = 0.f; bz = 0.f; }
            else                  { bx = 0.f; by = 1.f; bz = 0.f; }
            float cx = uy * bz - uz * by;
            float cy = uz * bx - ux * bz;
            float cz = ux * by - uy * bx;
            float cn = sqrtf(cx * cx + cy * cy + cz * cz);
            float cd = fmaxf(cn, EPSF);
            cx /= cd; cy /= cd; cz /= cd;
            float K2[9] = {0.f, -cz, cy,  cz, 0.f, -cx,  -cy, cx, 0.f};
            float K2K2[9];
            for (int i = 0; i < 3; ++i)
                for (int j = 0; j < 3; ++j) {
                    float s2 = 0.f;
                    for (int l = 0; l < 3; ++l) s2 += K2[i * 3 + l] * K2[l * 3 + j];
                    K2K2[i * 3 + j] = s2;
                }
            for (int i = 0; i < 9; ++i) {
                float I = (i == 0 || i == 4 || i == 8) ? 1.f : 0.f;
                R[i] = I + 2.f * K2K2[i];
            }
        } else if (dot > 0.f) {
            for (int i = 0; i < 9; ++i) R[i] = (i == 0 || i == 4 || i == 8) ? 1.f : 0.f;
        }
    }
    float ms0 = sums[0] / (float)NPTS, ms1 = sums[1] / (float)NPTS, ms2 = sums[2] / (float)NPTS;
    float mt0 = sums[3] / (float)NPTS, mt1 = sums[4] / (float)NPTS, mt2 = sums[5] / (float)NPTS;
    for (int i = 0; i < 9; ++i) R_out[i] = R[i];
    t_out[0] = mt0 - (R[0] * ms0 + R[1] * ms1 + R[2] * ms2);
    t_out[1] = mt1 - (R[3] * ms0 + R[4] * ms1 + R[5] * ms2);
    t_out[2] = mt2 - (R[6] * ms0 + R[7] * ms1 + R[8] * ms2);
}

// ============================================================================
// Redundant per-block means + R/t (bit-exact-proven R10-R13). sf needs
// >= 1548 floats; leaves R/t in sf[1536..1547].
// ============================================================================
__device__ __forceinline__ void block_means_rt(
    const float* __restrict__ S, const float* __restrict__ T,
    const float* __restrict__ g_p, const float* __restrict__ g_q,
    int b, int tid, float* sf) {
    float acc[6] = {0.f, 0.f, 0.f, 0.f, 0.f, 0.f};
    if (tid < 256) {
        for (int n = tid; n < NPTS; n += 256) {
            acc[0] += S[n]; acc[1] += S[NPTS + n]; acc[2] += S[2 * NPTS + n];
            acc[3] += T[n]; acc[4] += T[NPTS + n]; acc[5] += T[2 * NPTS + n];
        }
    }
    if (tid < 256) {
        #pragma unroll
        for (int c = 0; c < 6; ++c) sf[c * 256 + tid] = acc[c];
    }
    __syncthreads();
    for (int s = 128; s > 0; s >>= 1) {
        if (tid < s) {
            #pragma unroll
            for (int c = 0; c < 6; ++c) sf[c * 256 + tid] += sf[c * 256 + tid + s];
        }
        __syncthreads();
    }
    if (tid == 0) {
        float sums[6];
        #pragma unroll
        for (int c = 0; c < 6; ++c) sums[c] = sf[c * 256];
        gravity_align_rt(g_p, g_q, sums, b, sf + 1536, sf + 1545);
    }
    __syncthreads();
}

// ============================================================================
// kPack: means + R/t + pack own/stage arrays. Grid NB x 1024.
// Own arrays carry w = ||.||^2 (proven own expr); stage arrays carry
// w = (||.||^2) * -0.5f (proven staging expr). All transforms byte-identical
// to the R10/R12-proven staging code.
// ============================================================================
__global__ __launch_bounds__(1024, 8) void kPack(
    const float* __restrict__ src, const float* __restrict__ tgt,
    const float* __restrict__ g_p, const float* __restrict__ g_q,
    float4* __restrict__ Pown, float4* __restrict__ Pstage,
    float4* __restrict__ Qown, float4* __restrict__ Qstage) {
    const int b = blockIdx.x;
    const int tid = threadIdx.x;
    const float* S = src + (size_t)b * 3 * NPTS;
    const float* T = tgt + (size_t)b * 3 * NPTS;

    __shared__ float sf[1548];
    block_means_rt(S, T, g_p, g_q, b, tid, sf);
    const float R0 = sf[1536], R1 = sf[1537], R2 = sf[1538];
    const float R3 = sf[1539], R4 = sf[1540], R5 = sf[1541];
    const float R6 = sf[1542], R7 = sf[1543], R8 = sf[1544];
    const float t0 = sf[1545], t1 = sf[1546], t2 = sf[1547];

    for (int n = tid; n < NPTS; n += 1024) {
        float s0 = S[n], s1 = S[NPTS + n], s2 = S[2 * NPTS + n];
        float p0 = R0 * s0 + R1 * s1 + R2 * s2 + t0;
        float p1 = R3 * s0 + R4 * s1 + R5 * s2 + t1;
        float p2 = R6 * s0 + R7 * s1 + R8 * s2 + t2;
        float pp = p0 * p0 + p1 * p1 + p2 * p2;
        Pown[b * NPTS + n] = make_float4(p0, p1, p2, pp);
        Pstage[b * NPTS + n] = make_float4(p0, p1, p2, (p0 * p0 + p1 * p1 + p2 * p2) * -0.5f);

        float q0 = T[n], q1 = T[NPTS + n], q2 = T[2 * NPTS + n];
        float qq = q0 * q0 + q1 * q1 + q2 * q2;
        Qown[b * NPTS + n] = make_float4(q0, q1, q2, qq);
        Qstage[b * NPTS + n] = make_float4(q0, q1, q2, (q0 * q0 + q1 * q1 + q2 * q2) * -0.5f);
    }
}

// ============================================================================
// kA: NN scan via SCALAR-path candidate broadcast (no LDS stage).
// Grid (64, NB, 2) x 1024, 8KB LDS (combine only) -> high occupancy.
// R13 post-mortem: LDS broadcast ds_read costs ~12cyc/16 useful bytes and
// pinned the scan at 41us across configs. Candidate index is wave-uniform
// (stripe), forced via readfirstlane so the compiler can use the scalar
// (s_load/K$) or uniform-address path instead of the LDS pipe.
// Traversal/tie rules verbatim proven: 16 stripes x 256 ascending m,
// strict >, stripe-order combine -> first-occurrence argmin bit-exact.
// ============================================================================
__global__ __launch_bounds__(1024, 8) void kA(
    const float4* __restrict__ Pown, const float4* __restrict__ Pstage,
    const float4* __restrict__ Qown, const float4* __restrict__ Qstage,
    float* __restrict__ nnp, int* __restrict__ idxp,
    float* __restrict__ nnq, int* __restrict__ idxq) {
    const int b = blockIdx.y;
    const int z = blockIdx.z;
    const int tid = threadIdx.x;
    const float4* own = z ? Qown : Pown;
    const float4* stg = z ? Pstage : Qstage;

    const int nl = tid & 63;
    const int stripe = tid >> 6;                  // wave-uniform
    const int n = blockIdx.x * 64 + nl;
    const float4 p = own[b * NPTS + n];

    const int m0u = __builtin_amdgcn_readfirstlane(stripe << 8);
    const float4* sb = stg + b * NPTS + m0u;      // wave-uniform base

    float best = -3.4e38f;
    int bi = m0u;
    #pragma unroll 4
    for (int m = 0; m < 256; ++m) {
        float4 q = sb[m];                         // uniform addr -> scalar/K$ path
        float s = fmaf(p.x, q.x, fmaf(p.y, q.y, fmaf(p.z, q.z, q.w)));
        if (s > best) { best = s; bi = m0u + m; }
    }

    __shared__ float combd[1024];
    __shared__ int combi[1024];
    combd[tid] = best;
    combi[tid] = bi;
    __syncthreads();
    if (stripe == 0) {
        for (int s2 = 1; s2 < 16; ++s2) {
            float d2 = combd[s2 * 64 + nl];
            int i2 = combi[s2 * 64 + nl];
            if (d2 > best) { best = d2; bi = i2; }  // ties: lower m wins
        }
        float d = fmaf(-2.0f, best, p.w);
        float* nn = z ? nnq : nnp;
        int* idx = z ? idxq : idxp;
        nn[b * NPTS + n] = sqrtf(fmaxf(d, 0.f) + EPSF);
        idx[b * NPTS + n] = bi;
    }
}

// ============================================================================
// kB: redundant means + redundant radix median + weights (verbatim R12,
// proven bit-exact and ~6us). Grid (64, NB, 2) x 1024.
// ============================================================================
__global__ __launch_bounds__(1024, 8) void kB(
    const float* __restrict__ src, const float* __restrict__ tgt,
    const float* __restrict__ nnp, const float* __restrict__ nnq,
    const int* __restrict__ idxp, const int* __restrict__ idxq,
    const float* __restrict__ src_n, const float* __restrict__ tgt_n,
    const float* __restrict__ g_p, const float* __restrict__ g_q,
    const float* __restrict__ k_p, const float* __restrict__ k_q,
    float* __restrict__ out) {
    const int x = blockIdx.x;
    const int b = blockIdx.y;
    const int z = blockIdx.z;
    const int tid = threadIdx.x;
    const int wid = tid >> 6;
    const int lane = tid & 63;
    const float* S = src + (size_t)b * 3 * NPTS;
    const float* T = tgt + (size_t)b * 3 * NPTS;
    const float* a = (z ? nnq : nnp) + b * NPTS;

    __shared__ float msc[1548];
    __shared__ int hist[16][256];
    __shared__ int tot[256];
    __shared__ int digit_s, base_s;

    block_means_rt(S, T, g_p, g_q, b, tid, msc);
    const float R0 = msc[1536], R1 = msc[1537], R2 = msc[1538];
    const float R3 = msc[1539], R4 = msc[1540], R5 = msc[1541];
    const float R6 = msc[1542], R7 = msc[1543], R8 = msc[1544];

    unsigned int v[4];
    #pragma unroll
    for (int j = 0; j < 4; ++j)
        v[j] = __float_as_uint(a[tid + j * 1024]);  // positive: uint order == float order

    const int shifts[4]   = {23, 15, 7, 0};
    const unsigned him[4] = {0x00000000u, 0x7F800000u, 0x7FFF8000u, 0x7FFFFF80u};
    const unsigned dm[4]  = {0xFFu, 0xFFu, 0xFFu, 0x7Fu};

    unsigned int prefix = 0u;
    int rank = 2047;

    for (int p = 0; p < 4; ++p) {
        const int sh = shifts[p];
        const unsigned himask = him[p];
        const unsigned dmask = dm[p];

        for (int k2 = lane; k2 < 256; k2 += 64) hist[wid][k2] = 0;
        __syncthreads();

        #pragma unroll
        for (int j = 0; j < 4; ++j) {
            if ((v[j] & himask) == prefix)
                atomicAdd(&hist[wid][(v[j] >> sh) & dmask], 1);
        }
        __syncthreads();

        if (tid < 256) {
            int t = 0;
            #pragma unroll
            for (int w = 0; w < 16; ++w) t += hist[w][tid];
            tot[tid] = t;
        }
        __syncthreads();

        if (wid == 0) {
            int c0 = tot[4 * lane + 0], c1 = tot[4 * lane + 1];
            int c2 = tot[4 * lane + 2], c3 = tot[4 * lane + 3];
            int s = c0 + c1 + c2 + c3;
            int incl = s;
            #pragma unroll
            for (int o = 1; o < 64; o <<= 1) {
                int t = __shfl_up(incl, o, 64);
                if (lane >= o) incl += t;
            }
            int base = incl - s;
            int cs[4] = {c0, c1, c2, c3};
            #pragma unroll
            for (int k2 = 0; k2 < 4; ++k2) {
                if (cs[k2] > 0 && rank >= base && rank < base + cs[k2]) {
                    digit_s = 4 * lane + k2;   // unique writer
                    base_s = base;
                }
                base += cs[k2];
            }
        }
        __syncthreads();
        prefix |= ((unsigned)digit_s) << sh;
        rank -= base_s;
        __syncthreads();
    }
    const float tauv = 3.0f * __uint_as_float(prefix);

    if (tid < 64) {
        const int n = x * 64 + tid;
        const float* SN = src_n + (size_t)b * 3 * NPTS;
        const float* TN = tgt_n + (size_t)b * 3 * NPTS;
        const float gx = g_q[3 * b + 0], gy = g_q[3 * b + 1], gz = g_q[3 * b + 2];
        const float kp = k_p[b], kq = k_q[b];
        const float keff = kp * kq / (kp + kq + EPSF);

        float w;
        if (z == 0) {
            float a0 = SN[n], a1 = SN[NPTS + n], a2 = SN[2 * NPTS + n];
            float snx = R0 * a0 + R1 * a1 + R2 * a2;
            float sny = R3 * a0 + R4 * a1 + R5 * a2;
            float snz = R6 * a0 + R7 * a1 + R8 * a2;
            float inc = snx * gx + sny * gy + snz * gz;
            int jj = idxp[b * NPTS + n];
            float tnx = TN[jj], tny = TN[NPTS + jj], tnz = TN[2 * NPTS + jj];
            float incr = tnx * gx + tny * gy + tnz * gz;
            float diff = inc - incr;
            float arg = 9.0f - keff * diff * diff;
            float sig = 1.f / (1.f + expf(-arg));
            float geom = (a[n] <= tauv) ? 1.f : 0.f;
            w = sig * geom;
        } else {
            float tnx = TN[n], tny = TN[NPTS + n], tnz = TN[2 * NPTS + n];
            float inc = tnx * gx + tny * gy + tnz * gz;
            int jj = idxq[b * NPTS + n];
            float a0 = SN[jj], a1 = SN[NPTS + jj], a2 = SN[2 * NPTS + jj];
            float snx = R0 * a0 + R1 * a1 + R2 * a2;
            float sny = R3 * a0 + R4 * a1 + R5 * a2;
            float snz = R6 * a0 + R7 * a1 + R8 * a2;
            float incr = snx * gx + sny * gy + snz * gz;
            float diff = inc - incr;
            float arg = 9.0f - keff * diff * diff;
            float sig = 1.f / (1.f + expf(-arg));
            float geom = (a[n] <= tauv) ? 1.f : 0.f;
            w = sig * geom;
        }
        out[z * (NB * NPTS) + b * NPTS + n] = w;
    }
}

extern "C" void kernel_launch(void* const* d_in, const int* in_sizes, int n_in,
                              void* d_out, int out_size, void* d_ws, size_t ws_size,
                              hipStream_t stream) {
    const float* src   = (const float*)d_in[0];
    const float* tgt   = (const float*)d_in[1];
    const float* src_n = (const float*)d_in[2];
    const float* tgt_n = (const float*)d_in[3];
    const float* g_p   = (const float*)d_in[4];
    const float* k_p   = (const float*)d_in[5];
    const float* g_q   = (const float*)d_in[6];
    const float* k_q   = (const float*)d_in[7];
    float* out = (float*)d_out;

    const int BN = NB * NPTS;
    float4* Pown   = (float4*)d_ws;
    float4* Pstage = Pown + BN;
    float4* Qown   = Pstage + BN;
    float4* Qstage = Qown + BN;
    float* nnp = (float*)(Qstage + BN);
    float* nnq = nnp + BN;
    int* idxp = (int*)(nnq + BN);
    int* idxq = idxp + BN;

    kPack<<<dim3(NB), dim3(1024), 0, stream>>>(src, tgt, g_p, g_q,
                                               Pown, Pstage, Qown, Qstage);
    kA<<<dim3(NPTS / 64, NB, 2), dim3(1024), 0, stream>>>(Pown, Pstage, Qown, Qstage,
                                                          nnp, idxp, nnq, idxq);
    kB<<<dim3(NPTS / 64, NB, 2), dim3(1024), 0, stream>>>(src, tgt, nnp, nnq,
                                                          idxp, idxq, src_n, tgt_n,
                                                          g_p, g_q, k_p, k_q, out);
}

// Round 15
// 46.781 us; speedup vs baseline: 1.4188x; 1.4188x over previous
//
#include <hip/hip_runtime.h>
#include <math.h>

#define NPTS 4096
#define NB 4
#define EPSF 1e-6f

// ============================================================================
// gravity_align + t_center (exact reference arithmetic; bit-exact R1-R14).
// ============================================================================
__device__ __forceinline__ void gravity_align_rt(
    const float* __restrict__ g_p, const float* __restrict__ g_q,
    const float* sums, int b, float* R_out, float* t_out) {
    float gpx = g_p[3 * b + 0], gpy = g_p[3 * b + 1], gpz = g_p[3 * b + 2];
    float gqx = g_q[3 * b + 0], gqy = g_q[3 * b + 1], gqz = g_q[3 * b + 2];
    float nu = sqrtf(gpx * gpx + gpy * gpy + gpz * gpz);
    float du = fmaxf(nu, EPSF);
    float ux = gpx / du, uy = gpy / du, uz = gpz / du;
    float nv = sqrtf(gqx * gqx + gqy * gqy + gqz * gqz);
    float dv = fmaxf(nv, EPSF);
    float vx = gqx / dv, vy = gqy / dv, vz = gqz / dv;

    float ax = uy * vz - uz * vy;
    float ay = uz * vx - ux * vz;
    float az = ux * vy - uy * vx;
    float an = sqrtf(ax * ax + ay * ay + az * az);
    float dot = ux * vx + uy * vy + uz * vz;
    dot = fminf(1.0f, fmaxf(-1.0f, dot));
    bool parallel = (an < 1e-6f);

    float kx = ax / (an + EPSF), ky = ay / (an + EPSF), kz = az / (an + EPSF);
    float theta = acosf(dot);
    float st = sinf(theta), ct = cosf(theta);

    float K[9] = {0.f, -kz, ky,  kz, 0.f, -kx,  -ky, kx, 0.f};
    float KK[9];
    for (int i = 0; i < 3; ++i)
        for (int j = 0; j < 3; ++j) {
            float s2 = 0.f;
            for (int l = 0; l < 3; ++l) s2 += K[i * 3 + l] * K[l * 3 + j];
            KK[i * 3 + j] = s2;
        }
    float R[9];
    for (int i = 0; i < 9; ++i) {
        float I = (i == 0 || i == 4 || i == 8) ? 1.f : 0.f;
        R[i] = I + st * K[i] + (1.f - ct) * KK[i];
    }
    if (parallel) {
        if (dot < 0.f) {
            float bx, by, bz;
            if (fabsf(ux) < 0.9f) { bx = 1.f; by = 0.f; bz = 0.f; }
            else                  { bx = 0.f; by = 1.f; bz = 0.f; }
            float cx = uy * bz - uz * by;
            float cy = uz * bx - ux * bz;
            float cz = ux * by - uy * bx;
            float cn = sqrtf(cx * cx + cy * cy + cz * cz);
            float cd = fmaxf(cn, EPSF);
            cx /= cd; cy /= cd; cz /= cd;
            float K2[9] = {0.f, -cz, cy,  cz, 0.f, -cx,  -cy, cx, 0.f};
            float K2K2[9];
            for (int i = 0; i < 3; ++i)
                for (int j = 0; j < 3; ++j) {
                    float s2 = 0.f;
                    for (int l = 0; l < 3; ++l) s2 += K2[i * 3 + l] * K2[l * 3 + j];
                    K2K2[i * 3 + j] = s2;
                }
            for (int i = 0; i < 9; ++i) {
                float I = (i == 0 || i == 4 || i == 8) ? 1.f : 0.f;
                R[i] = I + 2.f * K2K2[i];
            }
        } else if (dot > 0.f) {
            for (int i = 0; i < 9; ++i) R[i] = (i == 0 || i == 4 || i == 8) ? 1.f : 0.f;
        }
    }
    float ms0 = sums[0] / (float)NPTS, ms1 = sums[1] / (float)NPTS, ms2 = sums[2] / (float)NPTS;
    float mt0 = sums[3] / (float)NPTS, mt1 = sums[4] / (float)NPTS, mt2 = sums[5] / (float)NPTS;
    for (int i = 0; i < 9; ++i) R_out[i] = R[i];
    t_out[0] = mt0 - (R[0] * ms0 + R[1] * ms1 + R[2] * ms2);
    t_out[1] = mt1 - (R[3] * ms0 + R[4] * ms1 + R[5] * ms2);
    t_out[2] = mt2 - (R[6] * ms0 + R[7] * ms1 + R[8] * ms2);
}

// ============================================================================
// K0a: per-batch means + R/t -> global Rt (verbatim R11, proven in the
// 46.6us run). Grid NB x 256.
// ============================================================================
__global__ void k0a_rt(const float* __restrict__ src, const float* __restrict__ tgt,
                       const float* __restrict__ g_p, const float* __restrict__ g_q,
                       float* __restrict__ Rt) {
    const int b = blockIdx.x;
    const int tid = threadIdx.x;
    const float* S = src + (size_t)b * 3 * NPTS;
    const float* T = tgt + (size_t)b * 3 * NPTS;

    float acc[6] = {0.f, 0.f, 0.f, 0.f, 0.f, 0.f};
    for (int n = tid; n < NPTS; n += 256) {
        acc[0] += S[n]; acc[1] += S[NPTS + n]; acc[2] += S[2 * NPTS + n];
        acc[3] += T[n]; acc[4] += T[NPTS + n]; acc[5] += T[2 * NPTS + n];
    }
    __shared__ float red[256];
    __shared__ float sums[6];
    for (int c = 0; c < 6; ++c) {
        red[tid] = acc[c];
        __syncthreads();
        for (int s = 128; s > 0; s >>= 1) {
            if (tid < s) red[tid] += red[tid + s];
            __syncthreads();
        }
        if (tid == 0) sums[c] = red[0];
        __syncthreads();
    }
    if (tid == 0) {
        float Rg[9], tc[3];
        gravity_align_rt(g_p, g_q, sums, b, Rg, tc);
        for (int i = 0; i < 9; ++i) Rt[b * 16 + i] = Rg[i];
        Rt[b * 16 + 9]  = tc[0];
        Rt[b * 16 + 10] = tc[1];
        Rt[b * 16 + 11] = tc[2];
    }
}

// ============================================================================
// kA: NN scan, V=2 own-points per lane (register reuse: one ds_read feeds
// two score evals — the only structural escape from the per-CU LDS-pipe
// floor identified in R12-R14). Grid (32, NB, 2) = 256 blocks (1/CU),
// 1024 thr, 64KB stage from raw (R10/R11-proven exprs). Scan order per
// point verbatim proven: 16 stripes x 256 ascending, strict >, dual
// combine in stripe order (R8-proven) -> first-occurrence argmin bit-exact.
// ============================================================================
__global__ __launch_bounds__(1024, 4) void kA(
    const float* __restrict__ src, const float* __restrict__ tgt,
    const float* __restrict__ Rt,
    float* __restrict__ nnp, int* __restrict__ idxp,
    float* __restrict__ nnq, int* __restrict__ idxq) {
    const int x = blockIdx.x;
    const int b = blockIdx.y;
    const int z = blockIdx.z;
    const int tid = threadIdx.x;
    const float* S = src + (size_t)b * 3 * NPTS;
    const float* T = tgt + (size_t)b * 3 * NPTS;
    const float R0 = Rt[b*16+0], R1 = Rt[b*16+1], R2 = Rt[b*16+2];
    const float R3 = Rt[b*16+3], R4 = Rt[b*16+4], R5 = Rt[b*16+5];
    const float R6 = Rt[b*16+6], R7 = Rt[b*16+7], R8 = Rt[b*16+8];
    const float t0 = Rt[b*16+9], t1 = Rt[b*16+10], t2 = Rt[b*16+11];

    __shared__ float4 stage4[NPTS];  // 64 KB
    float* sf = (float*)stage4;

    const int nl = tid & 63;
    const int stripe = tid >> 6;          // 0..15, each scans 256 candidates
    const int n0 = x * 128 + nl;          // own A; own B = n0 + 64
    float4 pA, pB;

    if (z == 0) {
        // stage = q-points from raw tgt (verbatim proven staging exprs)
        for (int i = tid; i < NPTS; i += 1024) {
            float q0 = T[i], q1 = T[NPTS + i], q2 = T[2 * NPTS + i];
            float w = (q0 * q0 + q1 * q1 + q2 * q2) * -0.5f;
            stage4[i] = make_float4(q0, q1, q2, w);
        }
        {
            float s0 = S[n0], s1 = S[NPTS + n0], s2 = S[2 * NPTS + n0];
            float p0 = R0 * s0 + R1 * s1 + R2 * s2 + t0;
            float p1 = R3 * s0 + R4 * s1 + R5 * s2 + t1;
            float p2 = R6 * s0 + R7 * s1 + R8 * s2 + t2;
            pA = make_float4(p0, p1, p2, p0 * p0 + p1 * p1 + p2 * p2);
        }
        {
            const int n2 = n0 + 64;
            float s0 = S[n2], s1 = S[NPTS + n2], s2 = S[2 * NPTS + n2];
            float p0 = R0 * s0 + R1 * s1 + R2 * s2 + t0;
            float p1 = R3 * s0 + R4 * s1 + R5 * s2 + t1;
            float p2 = R6 * s0 + R7 * s1 + R8 * s2 + t2;
            pB = make_float4(p0, p1, p2, p0 * p0 + p1 * p1 + p2 * p2);
        }
    } else {
        // stage = p-points (R-transformed src, verbatim proven)
        for (int i = tid; i < NPTS; i += 1024) {
            float s0 = S[i], s1 = S[NPTS + i], s2 = S[2 * NPTS + i];
            float p0 = R0 * s0 + R1 * s1 + R2 * s2 + t0;
            float p1 = R3 * s0 + R4 * s1 + R5 * s2 + t1;
            float p2 = R6 * s0 + R7 * s1 + R8 * s2 + t2;
            float w = (p0 * p0 + p1 * p1 + p2 * p2) * -0.5f;
            stage4[i] = make_float4(p0, p1, p2, w);
        }
        {
            float q0 = T[n0], q1 = T[NPTS + n0], q2 = T[2 * NPTS + n0];
            pA = make_float4(q0, q1, q2, q0 * q0 + q1 * q1 + q2 * q2);
        }
        {
            const int n2 = n0 + 64;
            float q0 = T[n2], q1 = T[NPTS + n2], q2 = T[2 * NPTS + n2];
            pB = make_float4(q0, q1, q2, q0 * q0 + q1 * q1 + q2 * q2);
        }
    }
    __syncthreads();

    const int m0 = stripe << 8;
    float bestA = -3.4e38f, bestB = -3.4e38f;
    int biA = m0, biB = m0;
    #pragma unroll 8
    for (int m = m0; m < m0 + 256; ++m) {
        float4 q = stage4[m];
        float sA = fmaf(pA.x, q.x, fmaf(pA.y, q.y, fmaf(pA.z, q.z, q.w)));
        float sB = fmaf(pB.x, q.x, fmaf(pB.y, q.y, fmaf(pB.z, q.z, q.w)));
        if (sA > bestA) { bestA = sA; biA = m; }
        if (sB > bestB) { bestB = sB; biB = m; }
    }
    __syncthreads();

    // R8-proven dual combine: 2x1024 floats + 2x1024 ints (16 KB in stage)
    float* combd = sf;
    int* combi = (int*)(sf + 2048);
    combd[tid] = bestA;
    combd[1024 + tid] = bestB;
    combi[tid] = biA;
    combi[1024 + tid] = biB;
    __syncthreads();
    if (stripe == 0) {
        for (int s2 = 1; s2 < 16; ++s2) {
            float dA = combd[s2 * 64 + nl];
            int iA = combi[s2 * 64 + nl];
            if (dA > bestA) { bestA = dA; biA = iA; }   // ties: lower stripe wins
            float dB = combd[1024 + s2 * 64 + nl];
            int iB = combi[1024 + s2 * 64 + nl];
            if (dB > bestB) { bestB = dB; biB = iB; }
        }
        float* nn = z ? nnq : nnp;
        int* idx = z ? idxq : idxp;
        float dA = fmaf(-2.0f, bestA, pA.w);
        nn[b * NPTS + n0] = sqrtf(fmaxf(dA, 0.f) + EPSF);
        idx[b * NPTS + n0] = biA;
        float dB = fmaf(-2.0f, bestB, pB.w);
        nn[b * NPTS + n0 + 64] = sqrtf(fmaxf(dB, 0.f) + EPSF);
        idx[b * NPTS + n0 + 64] = biB;
    }
}

// ============================================================================
// KCr: redundant median + weights (verbatim R11, proven in the 46.6us run).
// Grid (64, NB, 2) x 1024.
// ============================================================================
__global__ void kcr(const float* __restrict__ nnp, const float* __restrict__ nnq,
                    const int* __restrict__ idxp, const int* __restrict__ idxq,
                    const float* __restrict__ src_n, const float* __restrict__ tgt_n,
                    const float* __restrict__ Rt,
                    const float* __restrict__ g_q, const float* __restrict__ k_p,
                    const float* __restrict__ k_q, float* __restrict__ out) {
    const int x = blockIdx.x;
    const int b = blockIdx.y;
    const int z = blockIdx.z;
    const int tid = threadIdx.x;
    const int wid = tid >> 6;
    const int lane = tid & 63;
    const float* a = (z ? nnq : nnp) + b * NPTS;

    unsigned int v[4];
    #pragma unroll
    for (int j = 0; j < 4; ++j)
        v[j] = __float_as_uint(a[tid + j * 1024]);  // positive: uint order == float order

    __shared__ int hist[16][256];
    __shared__ int tot[256];
    __shared__ int digit_s, base_s;

    const int shifts[4]   = {23, 15, 7, 0};
    const unsigned him[4] = {0x00000000u, 0x7F800000u, 0x7FFF8000u, 0x7FFFFF80u};
    const unsigned dm[4]  = {0xFFu, 0xFFu, 0xFFu, 0x7Fu};

    unsigned int prefix = 0u;
    int rank = 2047;

    for (int p = 0; p < 4; ++p) {
        const int sh = shifts[p];
        const unsigned himask = him[p];
        const unsigned dmask = dm[p];

        for (int k2 = lane; k2 < 256; k2 += 64) hist[wid][k2] = 0;
        __syncthreads();

        #pragma unroll
        for (int j = 0; j < 4; ++j) {
            if ((v[j] & himask) == prefix)
                atomicAdd(&hist[wid][(v[j] >> sh) & dmask], 1);
        }
        __syncthreads();

        if (tid < 256) {
            int t = 0;
            #pragma unroll
            for (int w = 0; w < 16; ++w) t += hist[w][tid];
            tot[tid] = t;
        }
        __syncthreads();

        if (wid == 0) {
            int c0 = tot[4 * lane + 0], c1 = tot[4 * lane + 1];
            int c2 = tot[4 * lane + 2], c3 = tot[4 * lane + 3];
            int s = c0 + c1 + c2 + c3;
            int incl = s;
            #pragma unroll
            for (int o = 1; o < 64; o <<= 1) {
                int t = __shfl_up(incl, o, 64);
                if (lane >= o) incl += t;
            }
            int base = incl - s;
            int cs[4] = {c0, c1, c2, c3};
            #pragma unroll
            for (int k2 = 0; k2 < 4; ++k2) {
                if (cs[k2] > 0 && rank >= base && rank < base + cs[k2]) {
                    digit_s = 4 * lane + k2;   // unique writer
                    base_s = base;
                }
                base += cs[k2];
            }
        }
        __syncthreads();
        prefix |= ((unsigned)digit_s) << sh;
        rank -= base_s;
        __syncthreads();
    }
    const float tauv = 3.0f * __uint_as_float(prefix);

    if (tid < 64) {
        const int n = x * 64 + tid;
        const float* SN = src_n + (size_t)b * 3 * NPTS;
        const float* TN = tgt_n + (size_t)b * 3 * NPTS;
        const float R0 = Rt[b*16+0], R1 = Rt[b*16+1], R2 = Rt[b*16+2];
        const float R3 = Rt[b*16+3], R4 = Rt[b*16+4], R5 = Rt[b*16+5];
        const float R6 = Rt[b*16+6], R7 = Rt[b*16+7], R8 = Rt[b*16+8];
        const float gx = g_q[3 * b + 0], gy = g_q[3 * b + 1], gz = g_q[3 * b + 2];
        const float kp = k_p[b], kq = k_q[b];
        const float keff = kp * kq / (kp + kq + EPSF);

        float w;
        if (z == 0) {
            float a0 = SN[n], a1 = SN[NPTS + n], a2 = SN[2 * NPTS + n];
            float snx = R0 * a0 + R1 * a1 + R2 * a2;
            float sny = R3 * a0 + R4 * a1 + R5 * a2;
            float snz = R6 * a0 + R7 * a1 + R8 * a2;
            float inc = snx * gx + sny * gy + snz * gz;
            int jj = idxp[b * NPTS + n];
            float tnx = TN[jj], tny = TN[NPTS + jj], tnz = TN[2 * NPTS + jj];
            float incr = tnx * gx + tny * gy + tnz * gz;
            float diff = inc - incr;
            float arg = 9.0f - keff * diff * diff;
            float sig = 1.f / (1.f + expf(-arg));
            float geom = (a[n] <= tauv) ? 1.f : 0.f;
            w = sig * geom;
        } else {
            float tnx = TN[n], tny = TN[NPTS + n], tnz = TN[2 * NPTS + n];
            float inc = tnx * gx + tny * gy + tnz * gz;
            int jj = idxq[b * NPTS + n];
            float a0 = SN[jj], a1 = SN[NPTS + jj], a2 = SN[2 * NPTS + jj];
            float snx = R0 * a0 + R1 * a1 + R2 * a2;
            float sny = R3 * a0 + R4 * a1 + R5 * a2;
            float snz = R6 * a0 + R7 * a1 + R8 * a2;
            float incr = snx * gx + sny * gy + snz * gz;
            float diff = inc - incr;
            float arg = 9.0f - keff * diff * diff;
            float sig = 1.f / (1.f + expf(-arg));
            float geom = (a[n] <= tauv) ? 1.f : 0.f;
            w = sig * geom;
        }
        out[z * (NB * NPTS) + b * NPTS + n] = w;
    }
}

extern "C" void kernel_launch(void* const* d_in, const int* in_sizes, int n_in,
                              void* d_out, int out_size, void* d_ws, size_t ws_size,
                              hipStream_t stream) {
    const float* src   = (const float*)d_in[0];
    const float* tgt   = (const float*)d_in[1];
    const float* src_n = (const float*)d_in[2];
    const float* tgt_n = (const float*)d_in[3];
    const float* g_p   = (const float*)d_in[4];
    const float* k_p   = (const float*)d_in[5];
    const float* g_q   = (const float*)d_in[6];
    const float* k_q   = (const float*)d_in[7];
    float* out = (float*)d_out;

    const int BN = NB * NPTS;
    float* nnp = (float*)d_ws;
    float* nnq = nnp + BN;
    int* idxp = (int*)(nnq + BN);
    int* idxq = idxp + BN;
    float* Rt  = (float*)(idxq + BN);   // NB*16 floats

    k0a_rt<<<dim3(NB), dim3(256), 0, stream>>>(src, tgt, g_p, g_q, Rt);
    kA<<<dim3(NPTS / 128, NB, 2), dim3(1024), 0, stream>>>(src, tgt, Rt,
                                                           nnp, idxp, nnq, idxq);
    kcr<<<dim3(NPTS / 64, NB, 2), dim3(1024), 0, stream>>>(nnp, nnq, idxp, idxq,
                                                           src_n, tgt_n, Rt,
                                                           g_q, k_p, k_q, out);
}